// Round 5
// baseline (1212.929 us; speedup 1.0000x reference)
//
#include <hip/hip_runtime.h>

#define IN_C 300
#define OUT_C 200
#define NEG_SLOPE 0.2f

// W-stationary GEMM geometry
#define BMB 128  // rows per block (8 waves x 16)
#define BMW 16   // rows per wave
#define BKC 20   // K chunk (divides 300 and 200)

static inline int cdiv(long a, int b) { return (int)((a + b - 1) / b); }

// async global->LDS, 16B per lane. LDS dest = wave-uniform base + lane*16.
__device__ __forceinline__ void glds16(const float* g, float* l) {
  __builtin_amdgcn_global_load_lds(
      (const __attribute__((address_space(1))) void*)g,
      (__attribute__((address_space(3))) void*)l, 16, 0, 0);
}

// ---------------- utility ----------------
__global__ __launch_bounds__(256)
void zero_int_kernel(int* __restrict__ p, int n) {
  int i = blockIdx.x * blockDim.x + threadIdx.x;
  if (i < n) p[i] = 0;
}

__device__ __forceinline__ void edge_sd(const int* __restrict__ src,
                                        const int* __restrict__ dst,
                                        int i, int E, int& s, int& d) {
  if (i < E) { s = src[i]; d = dst[i]; } else { s = d = i - E; }
}

// pad W[K][200] -> Wpad[K][256] (cols 200..255 zero) for exact 1KB wave-issues
__global__ __launch_bounds__(256)
void padw_kernel(const float* __restrict__ W, float* __restrict__ Wpad, int K) {
  int idx = blockIdx.x * blockDim.x + threadIdx.x;  // float4 index over K*64
  if (idx >= K * 64) return;
  int k = idx >> 6, c = (idx & 63) * 4;
  float4 v = make_float4(0.f, 0.f, 0.f, 0.f);
  if (c < OUT_C) v = *(const float4*)(W + (long)k * OUT_C + c);
  *(float4*)(Wpad + (long)k * 256 + c) = v;
}

// ---------------- CSR build ----------------
__global__ __launch_bounds__(256)
void hist_kernel(const int* __restrict__ src, const int* __restrict__ dst,
                 int E, int ET, int* __restrict__ counts) {
  int i = blockIdx.x * blockDim.x + threadIdx.x;
  if (i >= ET) return;
  int s, d; edge_sd(src, dst, i, E, s, d);
  atomicAdd(counts + d, 1);
}

// inclusive scan, 1024 elems/block (256 thr x 4). out = rowptr+1.
__global__ __launch_bounds__(256)
void scan_a_kernel(const int* __restrict__ in, int n, int* __restrict__ out,
                   int* __restrict__ bsums) {
  __shared__ int lds[256];
  int t = threadIdx.x;
  int base = blockIdx.x * 1024 + t * 4;
  int v0 = (base + 0 < n) ? in[base + 0] : 0;
  int v1 = (base + 1 < n) ? in[base + 1] : 0;
  int v2 = (base + 2 < n) ? in[base + 2] : 0;
  int v3 = (base + 3 < n) ? in[base + 3] : 0;
  int s1 = v0 + v1, s2 = s1 + v2, s3 = s2 + v3;
  lds[t] = s3;
  __syncthreads();
  for (int o = 1; o < 256; o <<= 1) {
    int x = (t >= o) ? lds[t - o] : 0;
    __syncthreads();
    lds[t] += x;
    __syncthreads();
  }
  int pre = (t > 0) ? lds[t - 1] : 0;
  if (base + 0 < n) out[base + 0] = pre + v0;
  if (base + 1 < n) out[base + 1] = pre + s1;
  if (base + 2 < n) out[base + 2] = pre + s2;
  if (base + 3 < n) out[base + 3] = pre + s3;
  if (t == 255) bsums[blockIdx.x] = lds[255];
}

// single-block inclusive scan of block sums (nb <= 256)
__global__ __launch_bounds__(256)
void scan_b_kernel(int* __restrict__ bs, int nb) {
  __shared__ int lds[256];
  int t = threadIdx.x;
  lds[t] = (t < nb) ? bs[t] : 0;
  __syncthreads();
  for (int o = 1; o < 256; o <<= 1) {
    int x = (t >= o) ? lds[t - o] : 0;
    __syncthreads();
    lds[t] += x;
    __syncthreads();
  }
  if (t < nb) bs[t] = lds[t];
}

__global__ __launch_bounds__(256)
void scan_c_kernel(int* __restrict__ out, int n, const int* __restrict__ bs) {
  int i = blockIdx.x * blockDim.x + threadIdx.x;
  if (i >= n) return;
  int b = i >> 10;
  if (b > 0) out[i] += bs[b - 1];
}

__global__ __launch_bounds__(256)
void fill_kernel(const int* __restrict__ src, const int* __restrict__ dst,
                 int E, int ET, const int* __restrict__ rowptr,
                 int* __restrict__ cursor, int* __restrict__ csr_src) {
  int i = blockIdx.x * blockDim.x + threadIdx.x;
  if (i >= ET) return;
  int s, d; edge_sd(src, dst, i, E, s, d);
  int pos = rowptr[d] + atomicAdd(cursor + d, 1);
  csr_src[pos] = s;
}

// ---------------- dense projection + fused alpha dot-products ----------------
// H[N,OUT_C] = A[N,K] @ W[K,OUT_C]; asN = H.a_src; adN = H.a_dst.
// 8 waves (512 thr) x 16 rows = 128-row blocks: 16 waves/CU resident (2 blocks
// x 60 KB LDS), W-staging amortized over 8 waves. Double-buffered
// global_load_lds staging; pure fmaf inner loop; A reads are wave-uniform LDS
// broadcasts; W reads contiguous 16B/lane (conflict-free).
__global__ __launch_bounds__(512)
void gemm_ws_kernel(const float* __restrict__ A, const float* __restrict__ Wpad,
                    const float* __restrict__ a_src, const float* __restrict__ a_dst,
                    float* __restrict__ H, float* __restrict__ asN,
                    float* __restrict__ adN, int K, int N) {
  __shared__ float Ws[2][BKC][256];   // 2 x 20 KB
  __shared__ float As[2][BMB][BKC];   // 2 x 10 KB
  int t = threadIdx.x;
  int wave = t >> 6, lane = t & 63;
  int col = lane * 4;                 // padded col space
  long row0 = (long)blockIdx.x * BMB;
  int wrow = wave * BMW;

  // ---- hoisted staging pointers (advance per chunk; no per-chunk div) ----
  // W: wave stages rows {wave, wave+8, wave+16(<20)}; lane supplies 16B at +col.
  const float* sW = Wpad + (long)wave * 256 + col;
  // A: tile = 128 rows x 20 cols = 640 float4 issues; f -> row f/5, col (f%5)*4.
  int f0 = t;
  long ar0 = row0 + f0 / 5; if (ar0 >= N) ar0 = N - 1;   // clamp, stores masked
  const float* sA0 = A + ar0 * K + (f0 % 5) * 4;
  int f1 = 512 + t;                                      // only t<128 issues
  long ar1 = row0 + f1 / 5; if (ar1 >= N) ar1 = N - 1;
  const float* sA1 = A + ar1 * K + (f1 % 5) * 4;

  auto stage = [&](int buf) {
    #pragma unroll
    for (int j = 0; j < 3; ++j) {
      int r = wave + j * 8;
      if (r < BKC) glds16(sW + j * 8 * 256, &Ws[buf][r][0]);
    }
    glds16(sA0, &As[buf][0][0] + wave * 256);
    if (t < 128) glds16(sA1, &As[buf][0][0] + 2048 + wave * 256);
    sW += BKC * 256; sA0 += BKC; sA1 += BKC;
  };

  float4 acc[BMW];
  #pragma unroll
  for (int r = 0; r < BMW; ++r) acc[r] = make_float4(0.f, 0.f, 0.f, 0.f);

  const int nch = K / BKC;
  stage(0);
  int cur = 0;
  for (int ch = 0; ch < nch; ++ch) {
    __syncthreads();   // drains vmcnt: buf[cur] ready; prev compute done
    if (ch + 1 < nch) stage(cur ^ 1);   // in flight under this chunk's FMAs
    #pragma unroll
    for (int kk = 0; kk < BKC; kk += 4) {
      float4 w0 = *(float4*)&Ws[cur][kk + 0][col];
      float4 w1 = *(float4*)&Ws[cur][kk + 1][col];
      float4 w2 = *(float4*)&Ws[cur][kk + 2][col];
      float4 w3 = *(float4*)&Ws[cur][kk + 3][col];
      #pragma unroll
      for (int r = 0; r < BMW; ++r) {
        float4 a = *(float4*)&As[cur][wrow + r][kk];   // wave-uniform broadcast
        acc[r].x = fmaf(a.x, w0.x, acc[r].x);
        acc[r].x = fmaf(a.y, w1.x, acc[r].x);
        acc[r].x = fmaf(a.z, w2.x, acc[r].x);
        acc[r].x = fmaf(a.w, w3.x, acc[r].x);
        acc[r].y = fmaf(a.x, w0.y, acc[r].y);
        acc[r].y = fmaf(a.y, w1.y, acc[r].y);
        acc[r].y = fmaf(a.z, w2.y, acc[r].y);
        acc[r].y = fmaf(a.w, w3.y, acc[r].y);
        acc[r].z = fmaf(a.x, w0.z, acc[r].z);
        acc[r].z = fmaf(a.y, w1.z, acc[r].z);
        acc[r].z = fmaf(a.z, w2.z, acc[r].z);
        acc[r].z = fmaf(a.w, w3.z, acc[r].z);
        acc[r].w = fmaf(a.x, w0.w, acc[r].w);
        acc[r].w = fmaf(a.y, w1.w, acc[r].w);
        acc[r].w = fmaf(a.z, w2.w, acc[r].w);
        acc[r].w = fmaf(a.w, w3.w, acc[r].w);
      }
    }
    cur ^= 1;
  }

  // epilogue: H rows + fused alpha dot-products
  bool cok = col < OUT_C;
  #pragma unroll
  for (int r = 0; r < BMW; ++r) {
    long grow = row0 + wrow + r;
    if (cok && grow < N) *(float4*)(H + grow * OUT_C + col) = acc[r];
  }
  float4 vs = make_float4(0.f, 0.f, 0.f, 0.f);
  float4 vd = make_float4(0.f, 0.f, 0.f, 0.f);
  if (cok) {
    vs = *(const float4*)(a_src + col);
    vd = *(const float4*)(a_dst + col);
  }
  #pragma unroll
  for (int r = 0; r < BMW; ++r) {
    float ss = acc[r].x * vs.x + acc[r].y * vs.y + acc[r].z * vs.z + acc[r].w * vs.w;
    float sd = acc[r].x * vd.x + acc[r].y * vd.y + acc[r].z * vd.z + acc[r].w * vd.w;
    #pragma unroll
    for (int o = 32; o > 0; o >>= 1) {
      ss += __shfl_xor(ss, o);
      sd += __shfl_xor(sd, o);
    }
    long grow = row0 + wrow + r;
    if (lane == 0 && grow < N) { asN[grow] = ss; adN[grow] = sd; }
  }
}

// ---------------- fused segment-softmax + gather-aggregate + bias + relu ----
// One wave per destination node. SINGLE edge walk: softmax without max-sub
// (mathematically identical; scores are O(+-10) so exp is fp32-safe). se is
// accumulated redundantly in every lane (no reductions needed). Lane owns
// cols lane*4 (lanes 0..49 active on the float4 payload); normalize at store.
__global__ __launch_bounds__(256)
void gather_agg_kernel(const float* __restrict__ h, const float* __restrict__ asN,
                       const float* __restrict__ adN, const int* __restrict__ rowptr,
                       const int* __restrict__ csr_src, const float* __restrict__ bias,
                       float* __restrict__ out, int N) {
  int wid = (int)(((long)blockIdx.x * blockDim.x + threadIdx.x) >> 6);
  int lane = threadIdx.x & 63;
  if (wid >= N) return;
  int start = rowptr[wid], end = rowptr[wid + 1];
  float ad = adN[wid];
  int c = lane * 4;
  bool cok = c < OUT_C;
  const float* hc = h + c;

  float4 acc = make_float4(0.f, 0.f, 0.f, 0.f);
  float se = 0.f;
  int j = start;
  for (; j + 2 <= end; j += 2) {
    int s0 = csr_src[j], s1 = csr_src[j + 1];
    float e0 = asN[s0] + ad, e1 = asN[s1] + ad;
    e0 = e0 > 0.f ? e0 : NEG_SLOPE * e0;
    e1 = e1 > 0.f ? e1 : NEG_SLOPE * e1;
    float w0 = __expf(e0), w1 = __expf(e1);
    se += w0 + w1;
    if (cok) {
      float4 h0 = *(const float4*)(hc + (long)s0 * OUT_C);
      float4 h1 = *(const float4*)(hc + (long)s1 * OUT_C);
      acc.x = fmaf(w0, h0.x, acc.x); acc.x = fmaf(w1, h1.x, acc.x);
      acc.y = fmaf(w0, h0.y, acc.y); acc.y = fmaf(w1, h1.y, acc.y);
      acc.z = fmaf(w0, h0.z, acc.z); acc.z = fmaf(w1, h1.z, acc.z);
      acc.w = fmaf(w0, h0.w, acc.w); acc.w = fmaf(w1, h1.w, acc.w);
    }
  }
  if (j < end) {
    int s0 = csr_src[j];
    float e0 = asN[s0] + ad;
    e0 = e0 > 0.f ? e0 : NEG_SLOPE * e0;
    float w0 = __expf(e0);
    se += w0;
    if (cok) {
      float4 h0 = *(const float4*)(hc + (long)s0 * OUT_C);
      acc.x = fmaf(w0, h0.x, acc.x);
      acc.y = fmaf(w0, h0.y, acc.y);
      acc.z = fmaf(w0, h0.z, acc.z);
      acc.w = fmaf(w0, h0.w, acc.w);
    }
  }
  if (cok) {
    float inv = 1.0f / se;
    float4 bv = *(const float4*)(bias + c);
    float4 o;
    o.x = fmaxf(fmaf(acc.x, inv, bv.x), 0.f);
    o.y = fmaxf(fmaf(acc.y, inv, bv.y), 0.f);
    o.z = fmaxf(fmaf(acc.z, inv, bv.z), 0.f);
    o.w = fmaxf(fmaf(acc.w, inv, bv.w), 0.f);
    *(float4*)(out + (long)wid * OUT_C + c) = o;
  }
}

// ---------------- driver ----------------
static void run_layer(const float* xin, int K, const float* Wpad,
                      const float* a_s, const float* a_d, const float* b,
                      const int* rowptr, const int* csr_src, int N,
                      float* hbuf, float* asN, float* adN, float* outbuf,
                      hipStream_t stream) {
  gemm_ws_kernel<<<cdiv(N, BMB), 512, 0, stream>>>(xin, Wpad, a_s, a_d,
                                                   hbuf, asN, adN, K, N);
  gather_agg_kernel<<<cdiv((long)N * 64, 256), 256, 0, stream>>>(
      hbuf, asN, adN, rowptr, csr_src, b, outbuf, N);
}

extern "C" void kernel_launch(void* const* d_in, const int* in_sizes, int n_in,
                              void* d_out, int out_size, void* d_ws, size_t ws_size,
                              hipStream_t stream) {
  const float* x   = (const float*)d_in[0];
  const float* W0  = (const float*)d_in[1];
  const float* as0 = (const float*)d_in[2];
  const float* ad0 = (const float*)d_in[3];
  const float* b0  = (const float*)d_in[4];
  const float* W1  = (const float*)d_in[5];
  const float* as1 = (const float*)d_in[6];
  const float* ad1 = (const float*)d_in[7];
  const float* b1  = (const float*)d_in[8];
  const int*   ei  = (const int*)d_in[9];

  const int N  = in_sizes[0] / IN_C;
  const int E  = in_sizes[9] / 2;
  const int ET = E + N;
  const int* src = ei;
  const int* dst = ei + E;

  float* out = (float*)d_out;

  char* ws = (char*)d_ws;
  float* hbuf   = (float*)ws;                                  // N*OUT_C
  float* asN    = (float*)(ws + (size_t)N * OUT_C * 4);        // N
  float* adN    = asN + N;                                     // N
  int*   rowptr = (int*)(adN + N);                             // N+1
  int*   counts = rowptr + (N + 1);                            // N (also cursor)
  int*   bsums  = counts + N;                                  // 256
  int*   csrsrc = bsums + 256;                                 // ET
  // 16B-align the padded-W buffers (float4 accesses)
  size_t woff = ((size_t)(csrsrc + ET - (int*)ws) + 3) & ~(size_t)3;
  float* wpad0 = (float*)ws + woff;                            // IN_C*256
  float* wpad1 = wpad0 + (size_t)IN_C * 256;                   // OUT_C*256

  const int nb = cdiv(N, 1024);

  // ---- one-time: pad W matrices, build CSR (shared by both layers) ----
  padw_kernel<<<cdiv(IN_C * 64, 256), 256, 0, stream>>>(W0, wpad0, IN_C);
  padw_kernel<<<cdiv(OUT_C * 64, 256), 256, 0, stream>>>(W1, wpad1, OUT_C);
  zero_int_kernel<<<cdiv(N, 256), 256, 0, stream>>>(counts, N);
  hist_kernel<<<cdiv(ET, 256), 256, 0, stream>>>(src, dst, E, ET, counts);
  scan_a_kernel<<<nb, 256, 0, stream>>>(counts, N, rowptr + 1, bsums);
  scan_b_kernel<<<1, 256, 0, stream>>>(bsums, nb);
  scan_c_kernel<<<cdiv(N, 256), 256, 0, stream>>>(rowptr + 1, N, bsums);
  zero_int_kernel<<<1, 256, 0, stream>>>(rowptr, 1);
  zero_int_kernel<<<cdiv(N, 256), 256, 0, stream>>>(counts, N);  // reuse as cursor
  fill_kernel<<<cdiv(ET, 256), 256, 0, stream>>>(src, dst, E, ET, rowptr, counts, csrsrc);

  // ---- layer 0: x -> out ----
  run_layer(x, IN_C, wpad0, as0, ad0, b0, rowptr, csrsrc, N, hbuf, asN, adN, out, stream);
  // ---- layer 1: out -> out (gemm reads out before gather_agg rewrites it) ----
  run_layer(out, OUT_C, wpad1, as1, ad1, b1, rowptr, csrsrc, N, hbuf, asN, adN, out, stream);
}

// Round 6
// 1116.235 us; speedup vs baseline: 1.0866x; 1.0866x over previous
//
#include <hip/hip_runtime.h>

#define IN_C 300
#define OUT_C 200
#define NEG_SLOPE 0.2f

// W-stationary GEMM geometry
#define BMB 64   // rows per block (4 waves x 16)
#define BMW 16   // rows per wave
#define BKC 20   // K chunk (divides 300 and 200)
#define WF4 1000 // float4 slots per W chunk = 20*200/4

static inline int cdiv(long a, int b) { return (int)((a + b - 1) / b); }

// async global->LDS, 16B per lane. LDS dest = wave-uniform base + lane*16.
__device__ __forceinline__ void glds16(const float* g, float* l) {
  __builtin_amdgcn_global_load_lds(
      (const __attribute__((address_space(1))) void*)g,
      (__attribute__((address_space(3))) void*)l, 16, 0, 0);
}

// ---------------- utility ----------------
__global__ __launch_bounds__(256)
void zero_int_kernel(int* __restrict__ p, int n) {
  int i = blockIdx.x * blockDim.x + threadIdx.x;
  if (i < n) p[i] = 0;
}

__device__ __forceinline__ void edge_sd(const int* __restrict__ src,
                                        const int* __restrict__ dst,
                                        int i, int E, int& s, int& d) {
  if (i < E) { s = src[i]; d = dst[i]; } else { s = d = i - E; }
}

// ---------------- CSR build ----------------
__global__ __launch_bounds__(256)
void hist_kernel(const int* __restrict__ src, const int* __restrict__ dst,
                 int E, int ET, int* __restrict__ counts) {
  int i = blockIdx.x * blockDim.x + threadIdx.x;
  if (i >= ET) return;
  int s, d; edge_sd(src, dst, i, E, s, d);
  atomicAdd(counts + d, 1);
}

// inclusive scan, 1024 elems/block (256 thr x 4). out = rowptr+1.
__global__ __launch_bounds__(256)
void scan_a_kernel(const int* __restrict__ in, int n, int* __restrict__ out,
                   int* __restrict__ bsums) {
  __shared__ int lds[256];
  int t = threadIdx.x;
  int base = blockIdx.x * 1024 + t * 4;
  int v0 = (base + 0 < n) ? in[base + 0] : 0;
  int v1 = (base + 1 < n) ? in[base + 1] : 0;
  int v2 = (base + 2 < n) ? in[base + 2] : 0;
  int v3 = (base + 3 < n) ? in[base + 3] : 0;
  int s1 = v0 + v1, s2 = s1 + v2, s3 = s2 + v3;
  lds[t] = s3;
  __syncthreads();
  for (int o = 1; o < 256; o <<= 1) {
    int x = (t >= o) ? lds[t - o] : 0;
    __syncthreads();
    lds[t] += x;
    __syncthreads();
  }
  int pre = (t > 0) ? lds[t - 1] : 0;
  if (base + 0 < n) out[base + 0] = pre + v0;
  if (base + 1 < n) out[base + 1] = pre + s1;
  if (base + 2 < n) out[base + 2] = pre + s2;
  if (base + 3 < n) out[base + 3] = pre + s3;
  if (t == 255) bsums[blockIdx.x] = lds[255];
}

// single-block inclusive scan of block sums (nb <= 256)
__global__ __launch_bounds__(256)
void scan_b_kernel(int* __restrict__ bs, int nb) {
  __shared__ int lds[256];
  int t = threadIdx.x;
  lds[t] = (t < nb) ? bs[t] : 0;
  __syncthreads();
  for (int o = 1; o < 256; o <<= 1) {
    int x = (t >= o) ? lds[t - o] : 0;
    __syncthreads();
    lds[t] += x;
    __syncthreads();
  }
  if (t < nb) bs[t] = lds[t];
}

__global__ __launch_bounds__(256)
void scan_c_kernel(int* __restrict__ out, int n, const int* __restrict__ bs) {
  int i = blockIdx.x * blockDim.x + threadIdx.x;
  if (i >= n) return;
  int b = i >> 10;
  if (b > 0) out[i] += bs[b - 1];
}

__global__ __launch_bounds__(256)
void fill_kernel(const int* __restrict__ src, const int* __restrict__ dst,
                 int E, int ET, const int* __restrict__ rowptr,
                 int* __restrict__ cursor, int* __restrict__ csr_src) {
  int i = blockIdx.x * blockDim.x + threadIdx.x;
  if (i >= ET) return;
  int s, d; edge_sd(src, dst, i, E, s, d);
  int pos = rowptr[d] + atomicAdd(cursor + d, 1);
  csr_src[pos] = s;
}

// ---------------- dense projection + fused alpha dot-products ----------------
// H[N,OUT_C] = A[N,K] @ W[K,OUT_C]; asN = H.a_src; adN = H.a_dst.
// 4 waves x 16 rows. W chunk (20x200, contiguous 16KB in W) is staged via
// REGISTERS (pw0..pw3, issue-early/write-late): single LDS buffer for W, so
// LDS = 26.6 KB -> ~4-6 resident blocks/CU. A staged via global_load_lds,
// double-buffered. Per chunk: barrier[A] (drains loads issued a full compute
// phase ago, ~free) -> ds_write regs->Wf (vmcnt already 0) -> barrier[B]
// (lgkm only) -> issue next loads -> 1280 fmaf. A reads are wave-uniform LDS
// broadcasts; W reads contiguous 16B/lane; lanes>=50 compute garbage cols
// (masked at store).
__global__ __launch_bounds__(256)
void gemm_ws_kernel(const float* __restrict__ A, const float* __restrict__ W,
                    const float* __restrict__ a_src, const float* __restrict__ a_dst,
                    float* __restrict__ H, float* __restrict__ asN,
                    float* __restrict__ adN, int K, int N) {
  __shared__ float Wf[4096];          // 16.4 KB: flat W chunk [20][200] (+pad)
  __shared__ float As[2][BMB][BKC];   // 10.2 KB: A tiles, double-buffered
  int t = threadIdx.x;
  int wave = t >> 6, lane = t & 63;
  int col = lane * 4;                 // 0..252; cols >=200 are garbage lanes
  long row0 = (long)blockIdx.x * BMB;
  int wrow = wave * BMW;

  // ---- W reg-staging: thread t owns f4 slots {t, 256+t, 512+t, 768+t} ----
  const bool pw3ok = t < (WF4 - 768);   // 1000 = 3*256 + 232
  float4 pw0, pw1, pw2, pw3;
  const float* wsrc = W;                // advances 4000 floats per chunk
  auto loadW = [&]() {
    pw0 = *(const float4*)(wsrc + t * 4);
    pw1 = *(const float4*)(wsrc + 1024 + t * 4);
    pw2 = *(const float4*)(wsrc + 2048 + t * 4);
    if (pw3ok) pw3 = *(const float4*)(wsrc + 3072 + t * 4);
    wsrc += BKC * OUT_C;
  };
  auto writeW = [&]() {
    float4* wf4 = (float4*)Wf;
    wf4[t] = pw0; wf4[256 + t] = pw1; wf4[512 + t] = pw2;
    if (pw3ok) wf4[768 + t] = pw3;
  };

  // ---- A async staging: 320 f4/chunk; thread t covers f=t, f=256+t (t<64) --
  int f0 = t;
  long ar0 = row0 + f0 / 5; if (ar0 >= N) ar0 = N - 1;   // clamp, stores masked
  const float* sA0 = A + ar0 * K + (f0 % 5) * 4;
  int f1 = 256 + t;
  long ar1 = row0 + f1 / 5; if (ar1 >= N) ar1 = N - 1;
  const float* sA1 = A + ar1 * K + (f1 % 5) * 4;
  auto loadA = [&](int buf) {
    glds16(sA0, (float*)As[buf] + wave * 256);
    if (t < 64) glds16(sA1, (float*)As[buf] + 1024);
    sA0 += BKC; sA1 += BKC;
  };

  float4 acc[BMW];
  #pragma unroll
  for (int r = 0; r < BMW; ++r) acc[r] = make_float4(0.f, 0.f, 0.f, 0.f);

  const int nch = K / BKC;
  loadW();
  loadA(0);
  int cur = 0;
  for (int ch = 0; ch < nch; ++ch) {
    __syncthreads();   // [A] drains W reg-loads + A glds (issued ~2560cy ago)
    writeW();          // vmcnt already 0: no wait before the ds_writes
    __syncthreads();   // [B] Wf visible block-wide (lgkm drain only)
    if (ch + 1 < nch) { loadW(); loadA(cur ^ 1); }  // fly under the FMAs
    #pragma unroll
    for (int kk = 0; kk < BKC; kk += 4) {
      float4 w0 = *(float4*)&Wf[(kk + 0) * OUT_C + col];
      float4 w1 = *(float4*)&Wf[(kk + 1) * OUT_C + col];
      float4 w2 = *(float4*)&Wf[(kk + 2) * OUT_C + col];
      float4 w3 = *(float4*)&Wf[(kk + 3) * OUT_C + col];
      #pragma unroll
      for (int r = 0; r < BMW; ++r) {
        float4 a = *(float4*)&As[cur][wrow + r][kk];   // wave-uniform broadcast
        acc[r].x = fmaf(a.x, w0.x, acc[r].x);
        acc[r].x = fmaf(a.y, w1.x, acc[r].x);
        acc[r].x = fmaf(a.z, w2.x, acc[r].x);
        acc[r].x = fmaf(a.w, w3.x, acc[r].x);
        acc[r].y = fmaf(a.x, w0.y, acc[r].y);
        acc[r].y = fmaf(a.y, w1.y, acc[r].y);
        acc[r].y = fmaf(a.z, w2.y, acc[r].y);
        acc[r].y = fmaf(a.w, w3.y, acc[r].y);
        acc[r].z = fmaf(a.x, w0.z, acc[r].z);
        acc[r].z = fmaf(a.y, w1.z, acc[r].z);
        acc[r].z = fmaf(a.z, w2.z, acc[r].z);
        acc[r].z = fmaf(a.w, w3.z, acc[r].z);
        acc[r].w = fmaf(a.x, w0.w, acc[r].w);
        acc[r].w = fmaf(a.y, w1.w, acc[r].w);
        acc[r].w = fmaf(a.z, w2.w, acc[r].w);
        acc[r].w = fmaf(a.w, w3.w, acc[r].w);
      }
    }
    cur ^= 1;
  }

  // epilogue: H rows + fused alpha dot-products
  bool cok = col < OUT_C;
  #pragma unroll
  for (int r = 0; r < BMW; ++r) {
    long grow = row0 + wrow + r;
    if (cok && grow < N) *(float4*)(H + grow * OUT_C + col) = acc[r];
  }
  float4 vs = make_float4(0.f, 0.f, 0.f, 0.f);
  float4 vd = make_float4(0.f, 0.f, 0.f, 0.f);
  if (cok) {
    vs = *(const float4*)(a_src + col);
    vd = *(const float4*)(a_dst + col);
  }
  #pragma unroll
  for (int r = 0; r < BMW; ++r) {
    float ss = acc[r].x * vs.x + acc[r].y * vs.y + acc[r].z * vs.z + acc[r].w * vs.w;
    float sd = acc[r].x * vd.x + acc[r].y * vd.y + acc[r].z * vd.z + acc[r].w * vd.w;
    #pragma unroll
    for (int o = 32; o > 0; o >>= 1) {
      ss += __shfl_xor(ss, o);
      sd += __shfl_xor(sd, o);
    }
    long grow = row0 + wrow + r;
    if (lane == 0 && grow < N) { asN[grow] = ss; adN[grow] = sd; }
  }
}

// ---------------- fused segment-softmax + gather-aggregate + bias + relu ----
// One wave per destination node. Single edge walk (softmax without max-sub;
// scores O(+-10), fp32-safe). se accumulated redundantly per-lane. Edge walk
// unrolled x4: 16 float4 row-loads in flight (latency-bound loop).
__global__ __launch_bounds__(256)
void gather_agg_kernel(const float* __restrict__ h, const float* __restrict__ asN,
                       const float* __restrict__ adN, const int* __restrict__ rowptr,
                       const int* __restrict__ csr_src, const float* __restrict__ bias,
                       float* __restrict__ out, int N) {
  int wid = (int)(((long)blockIdx.x * blockDim.x + threadIdx.x) >> 6);
  int lane = threadIdx.x & 63;
  if (wid >= N) return;
  int start = rowptr[wid], end = rowptr[wid + 1];
  float ad = adN[wid];
  int c = lane * 4;
  bool cok = c < OUT_C;
  const float* hc = h + c;

  float4 acc = make_float4(0.f, 0.f, 0.f, 0.f);
  float se = 0.f;
  int j = start;
  for (; j + 4 <= end; j += 4) {
    int s0 = csr_src[j], s1 = csr_src[j + 1];
    int s2 = csr_src[j + 2], s3 = csr_src[j + 3];
    float e0 = asN[s0] + ad, e1 = asN[s1] + ad;
    float e2 = asN[s2] + ad, e3 = asN[s3] + ad;
    e0 = e0 > 0.f ? e0 : NEG_SLOPE * e0;
    e1 = e1 > 0.f ? e1 : NEG_SLOPE * e1;
    e2 = e2 > 0.f ? e2 : NEG_SLOPE * e2;
    e3 = e3 > 0.f ? e3 : NEG_SLOPE * e3;
    float w0 = __expf(e0), w1 = __expf(e1), w2 = __expf(e2), w3 = __expf(e3);
    se += (w0 + w1) + (w2 + w3);
    if (cok) {
      float4 h0 = *(const float4*)(hc + (long)s0 * OUT_C);
      float4 h1 = *(const float4*)(hc + (long)s1 * OUT_C);
      float4 h2 = *(const float4*)(hc + (long)s2 * OUT_C);
      float4 h3 = *(const float4*)(hc + (long)s3 * OUT_C);
      acc.x = fmaf(w0, h0.x, acc.x); acc.x = fmaf(w1, h1.x, acc.x);
      acc.x = fmaf(w2, h2.x, acc.x); acc.x = fmaf(w3, h3.x, acc.x);
      acc.y = fmaf(w0, h0.y, acc.y); acc.y = fmaf(w1, h1.y, acc.y);
      acc.y = fmaf(w2, h2.y, acc.y); acc.y = fmaf(w3, h3.y, acc.y);
      acc.z = fmaf(w0, h0.z, acc.z); acc.z = fmaf(w1, h1.z, acc.z);
      acc.z = fmaf(w2, h2.z, acc.z); acc.z = fmaf(w3, h3.z, acc.z);
      acc.w = fmaf(w0, h0.w, acc.w); acc.w = fmaf(w1, h1.w, acc.w);
      acc.w = fmaf(w2, h2.w, acc.w); acc.w = fmaf(w3, h3.w, acc.w);
    }
  }
  for (; j < end; ++j) {
    int s0 = csr_src[j];
    float e0 = asN[s0] + ad;
    e0 = e0 > 0.f ? e0 : NEG_SLOPE * e0;
    float w0 = __expf(e0);
    se += w0;
    if (cok) {
      float4 h0 = *(const float4*)(hc + (long)s0 * OUT_C);
      acc.x = fmaf(w0, h0.x, acc.x);
      acc.y = fmaf(w0, h0.y, acc.y);
      acc.z = fmaf(w0, h0.z, acc.z);
      acc.w = fmaf(w0, h0.w, acc.w);
    }
  }
  if (cok) {
    float inv = 1.0f / se;
    float4 bv = *(const float4*)(bias + c);
    float4 o;
    o.x = fmaxf(fmaf(acc.x, inv, bv.x), 0.f);
    o.y = fmaxf(fmaf(acc.y, inv, bv.y), 0.f);
    o.z = fmaxf(fmaf(acc.z, inv, bv.z), 0.f);
    o.w = fmaxf(fmaf(acc.w, inv, bv.w), 0.f);
    *(float4*)(out + (long)wid * OUT_C + c) = o;
  }
}

// ---------------- driver ----------------
static void run_layer(const float* xin, int K, const float* W,
                      const float* a_s, const float* a_d, const float* b,
                      const int* rowptr, const int* csr_src, int N,
                      float* hbuf, float* asN, float* adN, float* outbuf,
                      hipStream_t stream) {
  gemm_ws_kernel<<<cdiv(N, BMB), 256, 0, stream>>>(xin, W, a_s, a_d,
                                                   hbuf, asN, adN, K, N);
  gather_agg_kernel<<<cdiv((long)N * 64, 256), 256, 0, stream>>>(
      hbuf, asN, adN, rowptr, csr_src, b, outbuf, N);
}

extern "C" void kernel_launch(void* const* d_in, const int* in_sizes, int n_in,
                              void* d_out, int out_size, void* d_ws, size_t ws_size,
                              hipStream_t stream) {
  const float* x   = (const float*)d_in[0];
  const float* W0  = (const float*)d_in[1];
  const float* as0 = (const float*)d_in[2];
  const float* ad0 = (const float*)d_in[3];
  const float* b0  = (const float*)d_in[4];
  const float* W1  = (const float*)d_in[5];
  const float* as1 = (const float*)d_in[6];
  const float* ad1 = (const float*)d_in[7];
  const float* b1  = (const float*)d_in[8];
  const int*   ei  = (const int*)d_in[9];

  const int N  = in_sizes[0] / IN_C;
  const int E  = in_sizes[9] / 2;
  const int ET = E + N;
  const int* src = ei;
  const int* dst = ei + E;

  float* out = (float*)d_out;

  char* ws = (char*)d_ws;
  float* hbuf   = (float*)ws;                                  // N*OUT_C
  float* asN    = (float*)(ws + (size_t)N * OUT_C * 4);        // N
  float* adN    = asN + N;                                     // N
  int*   rowptr = (int*)(adN + N);                             // N+1
  int*   counts = rowptr + (N + 1);                            // N (also cursor)
  int*   bsums  = counts + N;                                  // 256
  int*   csrsrc = bsums + 256;                                 // ET

  const int nb = cdiv(N, 1024);

  // ---- one-time CSR build (shared by both layers) ----
  zero_int_kernel<<<cdiv(N, 256), 256, 0, stream>>>(counts, N);
  hist_kernel<<<cdiv(ET, 256), 256, 0, stream>>>(src, dst, E, ET, counts);
  scan_a_kernel<<<nb, 256, 0, stream>>>(counts, N, rowptr + 1, bsums);
  scan_b_kernel<<<1, 256, 0, stream>>>(bsums, nb);
  scan_c_kernel<<<cdiv(N, 256), 256, 0, stream>>>(rowptr + 1, N, bsums);
  zero_int_kernel<<<1, 256, 0, stream>>>(rowptr, 1);
  zero_int_kernel<<<cdiv(N, 256), 256, 0, stream>>>(counts, N);  // reuse as cursor
  fill_kernel<<<cdiv(ET, 256), 256, 0, stream>>>(src, dst, E, ET, rowptr, counts, csrsrc);

  // ---- layer 0: x -> out ----
  run_layer(x, IN_C, W0, as0, ad0, b0, rowptr, csrsrc, N, hbuf, asN, adN, out, stream);
  // ---- layer 1: out -> out (gemm reads out before gather_agg rewrites it) ----
  run_layer(out, OUT_C, W1, as1, ad1, b1, rowptr, csrsrc, N, hbuf, asN, adN, out, stream);
}